// Round 6
// baseline (510.128 us; speedup 1.0000x reference)
//
#include <hip/hip_runtime.h>

#define NB   8192
#define NF   2048
#define NC   345
#define NCP  384
#define EPSV 1e-5f

typedef __bf16 bf16x8 __attribute__((ext_vector_type(8)));
typedef float  f32x4  __attribute__((ext_vector_type(4)));

__device__ __forceinline__ float bs2f(unsigned int u) { return __uint_as_float(u << 16); }
__device__ __forceinline__ unsigned short f2bs(float f) {
    unsigned int u = __float_as_uint(f);
    u += 0x7fffu + ((u >> 16) & 1u);   // round-to-nearest-even
    return (unsigned short)(u >> 16);
}

#define GLD16(g, l)                                                                     \
    __builtin_amdgcn_global_load_lds((const __attribute__((address_space(1))) void*)(g),\
                                     (__attribute__((address_space(3))) void*)(l),      \
                                     16, 0, 0)

// ---------------- gather + cast x rows: xg[i] = bf16(x[order[i]]) ----------------
__global__ void k_gather(const float* __restrict__ x, const int* __restrict__ order,
                         unsigned short* __restrict__ xg) {
    const int row = blockIdx.x;
    const long src = order[row];
    const float4* xr = (const float4*)(x + src * 2048);
    float4 a = xr[threadIdx.x * 2 + 0];
    float4 b = xr[threadIdx.x * 2 + 1];
    uint4 o;
    o.x = (unsigned)f2bs(a.x) | ((unsigned)f2bs(a.y) << 16);
    o.y = (unsigned)f2bs(a.z) | ((unsigned)f2bs(a.w) << 16);
    o.z = (unsigned)f2bs(b.x) | ((unsigned)f2bs(b.y) << 16);
    o.w = (unsigned)f2bs(b.z) | ((unsigned)f2bs(b.w) << 16);
    ((uint4*)(xg + (long)row * 2048))[threadIdx.x] = o;
}

// ---------------- transpose+cast weights: Wt[n][k] = bf16(W[k][n]) ----------------
__global__ void k_transpose(const float* __restrict__ W, unsigned short* __restrict__ Wt,
                            int K, int N, int Npad) {
    __shared__ float tile[32][33];
    const int n0 = blockIdx.x * 32, k0 = blockIdx.y * 32;
    const int tx = threadIdx.x, ty = threadIdx.y;   // 32 x 8
    #pragma unroll
    for (int i = 0; i < 32; i += 8) {
        int n = n0 + tx, k = k0 + ty + i;
        tile[ty + i][tx] = (n < N) ? W[(long)k * N + n] : 0.f;
    }
    __syncthreads();
    #pragma unroll
    for (int i = 0; i < 32; i += 8) {
        int n = n0 + ty + i, k = k0 + tx;
        if (n < Npad) Wt[(long)n * K + k] = f2bs(tile[tx][ty + i]);
    }
}

// ============ 256x128 pipelined bf16 GEMM, 2 blocks/CU (occupancy) ============
// Round-4's proven conflict-free 16x16x32 phase code, retiled: BM=256 BN=128,
// grid 512 (2 blocks/CU), 3 LDS subtile buffers x 24KB = 72KB, 8 waves (4Mx2N),
// per-wave 64x64 (acc 64 AGPR), __launch_bounds__(512,4) caps regs at 128 so
// 4 waves/SIMD co-schedule (m114 overlap). Counted vmcnt(3), distance 2.
#define NOPX  ((void)0)
#define BARX  do { asm volatile("" ::: "memory"); __builtin_amdgcn_s_barrier(); \
                   asm volatile("" ::: "memory"); } while (0)
#define LGKM0 asm volatile("s_waitcnt lgkmcnt(0)" ::: "memory")
#define VMW3  asm volatile("s_waitcnt vmcnt(3)" ::: "memory")
#define VMW0  asm volatile("s_waitcnt vmcnt(0)" ::: "memory")

#define LDA4(bi) do { const unsigned short* A_ = &L[(bi) * 12288];                    \
    _Pragma("unroll") for (int m_ = 0; m_ < 4; m_++)                                  \
        av[m_] = *(const bf16x8*)&A_[(jA0 + m_ * 16) * 64 + sA * 8]; } while (0)

#define LDB2(bi, n0) do { const unsigned short* B_ = &L[(bi) * 12288 + 8192];         \
    _Pragma("unroll") for (int n_ = 0; n_ < 2; n_++)                                  \
        bv[(n0) + n_] = *(const bf16x8*)&B_[(((n0) + n_) * 16 + frow) * 64 + sB * 8]; \
    } while (0)

#define MM2(n0) do { _Pragma("unroll") for (int n_ = 0; n_ < 2; n_++)                 \
    _Pragma("unroll") for (int m_ = 0; m_ < 4; m_++)                                  \
        acc[m_][(n0) + n_] = __builtin_amdgcn_mfma_f32_16x16x32_bf16(                 \
            bv[(n0) + n_], av[m_], acc[m_][(n0) + n_], 0, 0, 0); } while (0)

#define PH(bi, SG_A, SG_B, VMW) do {                                                  \
    LDA4(bi); LDB2(bi, 0); SG_A;                                                      \
    BARX; LGKM0;                                                                      \
    __builtin_amdgcn_s_setprio(1); MM2(0); __builtin_amdgcn_s_setprio(0);             \
    BARX;                                                                             \
    LDB2(bi, 2); SG_B;                                                                \
    BARX; LGKM0;                                                                      \
    __builtin_amdgcn_s_setprio(1); MM2(2); __builtin_amdgcn_s_setprio(0);             \
    VMW; BARX; } while (0)

template <int RELU, int STATS>
__global__ __launch_bounds__(512, 4) void k_gemm256(
    const unsigned short* __restrict__ A,
    const unsigned short* __restrict__ Bt,
    const float* __restrict__ bias,
    unsigned short* __restrict__ C,
    float* __restrict__ stats) {
    constexpr int K = 2048, N = 2048;
    __shared__ unsigned short L[3 * 12288];   // 72 KiB: 3 bufs x (A 8K + B 4K shorts)
    const int tid  = threadIdx.x;
    const int lane = tid & 63;
    const int wv   = tid >> 6;       // 8 waves: 4M x 2N
    const int frow = lane & 15;
    const int kg   = lane >> 4;
    const int wm   = wv >> 1;        // 0..3 (64-row strip)
    const int wn   = wv & 1;         // 0..1 (64-col strip)
    const int sA   = (kg + 4 * (wm >> 1)) ^ (frow & 7);
    const int sB   = (kg + 4 * wn) ^ (frow & 7);
    const int jA0  = (wm & 1) * 64 + frow;

    // XCD-aware swizzle: 512 blocks = 8 XCD x 64; XCD x owns M-blocks 4x..4x+3.
    const int id  = blockIdx.x;
    const int xcd = id & 7, kid = id >> 3;          // kid 0..63
    const int brow = (xcd * 4 + (kid & 3)) * 256;   // 32 M-blocks
    const int bcol = (kid >> 2) * 128;              // 16 N-blocks

    // staging sources, pre-swizzled (linear LDS dest == swizzled read layout)
    const unsigned short* pA[2];
    const unsigned short* pB;
    #pragma unroll
    for (int i = 0; i < 2; i++) {
        const int q = tid + i * 512;            // A chunk 0..1023
        const int j = q >> 3;                   // 0..127
        const int u = (q & 7) ^ (j & 7);
        const int r = j + 128 * (u >> 2);
        pA[i] = A + (long)(brow + r) * K + (u & 3) * 8;
    }
    {
        const int q = tid;                      // B chunk 0..511
        const int j = q >> 3;                   // 0..63
        const int u = (q & 7) ^ (j & 7);
        const int r = j + 64 * (u >> 2);        // 0..127
        pB = Bt + (long)(bcol + r) * K + (u & 3) * 8;
    }

    f32x4 acc[4][4];
    #pragma unroll
    for (int m = 0; m < 4; m++)
        #pragma unroll
        for (int n = 0; n < 4; n++)
            #pragma unroll
            for (int r = 0; r < 4; r++) acc[m][n][r] = 0.f;

    auto stageA = [&](int bi, int s) {
        unsigned short* Lb = &L[bi * 12288];
        const int ko = s * 32;
        GLD16(pA[0] + ko, Lb + wv * 512);
        GLD16(pA[1] + ko, Lb + 4096 + wv * 512);
    };
    auto stageB = [&](int bi, int s) {
        unsigned short* Lb = &L[bi * 12288];
        const int ko = s * 32;
        GLD16(pB + ko, Lb + 8192 + wv * 512);
    };

    bf16x8 av[4], bv[4];

    // prologue: subtiles 0,1 staged; wait subtile 0 (3 of 6 loads left out)
    stageA(0, 0); stageB(0, 0); stageA(1, 1); stageB(1, 1);
    VMW3; BARX;

    // main: 64 subtiles, buffers rotate 0,1,2; stage t+2 inside subtile t
    for (int i = 0; i < 20; i++) {
        const int t = i * 3;
        PH(0, stageA(2, t + 2), stageB(2, t + 2), VMW3);
        PH(1, stageA(0, t + 3), stageB(0, t + 3), VMW3);
        PH(2, stageA(1, t + 4), stageB(1, t + 4), VMW3);
    }
    PH(0, stageA(2, 62), stageB(2, 62), VMW3);   // t=60
    PH(1, stageA(0, 63), stageB(0, 63), VMW3);   // t=61
    PH(2, NOPX, NOPX, VMW0);                     // t=62
    PH(0, NOPX, NOPX, NOPX);                     // t=63

    // epilogue: lane holds rows rbase+m*16, cols cbase+n*16+{0..3} (ushort4)
    const int rbase = brow + wm * 64 + frow;
    const int cbase = bcol + wn * 64 + kg * 4;
    #pragma unroll
    for (int n = 0; n < 4; n++) {
        const int col = cbase + n * 16;
        const float4 bb = *(const float4*)&bias[col];
        float s0 = 0.f, s1 = 0.f, s2 = 0.f, s3 = 0.f;
        float q0 = 0.f, q1 = 0.f, q2 = 0.f, q3 = 0.f;
        #pragma unroll
        for (int m = 0; m < 4; m++) {
            const long row = rbase + m * 16;
            float v0 = acc[m][n][0] + bb.x;
            float v1 = acc[m][n][1] + bb.y;
            float v2 = acc[m][n][2] + bb.z;
            float v3 = acc[m][n][3] + bb.w;
            if (STATS) { s0 += v0; q0 += v0 * v0; s1 += v1; q1 += v1 * v1;
                         s2 += v2; q2 += v2 * v2; s3 += v3; q3 += v3 * v3; }
            if (RELU) { v0 = fmaxf(v0, 0.f); v1 = fmaxf(v1, 0.f);
                        v2 = fmaxf(v2, 0.f); v3 = fmaxf(v3, 0.f); }
            ushort4 st; st.x = f2bs(v0); st.y = f2bs(v1); st.z = f2bs(v2); st.w = f2bs(v3);
            *(ushort4*)&C[row * N + col] = st;
        }
        if (STATS) {
            #pragma unroll
            for (int off = 1; off <= 8; off <<= 1) {
                s0 += __shfl_xor(s0, off); s1 += __shfl_xor(s1, off);
                s2 += __shfl_xor(s2, off); s3 += __shfl_xor(s3, off);
                q0 += __shfl_xor(q0, off); q1 += __shfl_xor(q1, off);
                q2 += __shfl_xor(q2, off); q3 += __shfl_xor(q3, off);
            }
            if (frow == 0) {   // lanes 0,16,32,48: kg 0..3, disjoint col sets
                atomicAdd(&stats[col + 0], s0); atomicAdd(&stats[col + 1], s1);
                atomicAdd(&stats[col + 2], s2); atomicAdd(&stats[col + 3], s3);
                atomicAdd(&stats[N + col + 0], q0); atomicAdd(&stats[N + col + 1], q1);
                atomicAdd(&stats[N + col + 2], q2); atomicAdd(&stats[N + col + 3], q3);
            }
        }
    }
}

// ---------------- 128x128 GEMM (classifier, f32 out) ----------------
template <int RELU, int F32OUT>
__global__ __launch_bounds__(256) void k_gemm(const unsigned short* __restrict__ A,
                                              const unsigned short* __restrict__ Bt,
                                              const float* __restrict__ bias,
                                              unsigned short* __restrict__ Cb,
                                              float* __restrict__ Cf,
                                              int M, int N, int K, int ldc) {
    constexpr int BK = 64;
    __shared__ unsigned short As[128 * BK];
    __shared__ unsigned short Bs[128 * BK];
    const int tid  = threadIdx.x;
    const int lane = tid & 63;
    const int wv   = tid >> 6;
    const int brow = blockIdx.x * 128;
    const int bcol = blockIdx.y * 128;
    const int wr   = (wv >> 1) * 64;
    const int wc   = (wv & 1) * 64;
    const int frow = lane & 15;
    const int kg   = lane >> 4;
    const int rx   = frow & 7;
    const int srow  = lane >> 3;
    const int sslot = (lane & 7) ^ srow;

    f32x4 acc[4][4];
    #pragma unroll
    for (int m = 0; m < 4; m++)
        #pragma unroll
        for (int n = 0; n < 4; n++)
            #pragma unroll
            for (int r = 0; r < 4; r++) acc[m][n][r] = 0.f;

    for (int kt = 0; kt < K; kt += BK) {
        #pragma unroll
        for (int i = 0; i < 4; i++) {
            const int c = wv * 4 + i;
            const int r = c * 8 + srow;
            GLD16(A + (long)(brow + r) * K + kt + sslot * 8, &As[c * 512]);
        }
        #pragma unroll
        for (int i = 0; i < 4; i++) {
            const int c = wv * 4 + i;
            const int r = c * 8 + srow;
            GLD16(Bt + (long)(bcol + r) * K + kt + sslot * 8, &Bs[c * 512]);
        }
        __syncthreads();
        #pragma unroll
        for (int kk = 0; kk < 2; kk++) {
            bf16x8 av[4], bv[4];
            #pragma unroll
            for (int m = 0; m < 4; m++) {
                const int row = wr + m * 16 + frow;
                av[m] = *(const bf16x8*)&As[row * BK + (((kk * 4 + kg) ^ rx) * 8)];
            }
            #pragma unroll
            for (int n = 0; n < 4; n++) {
                const int row = wc + n * 16 + frow;
                bv[n] = *(const bf16x8*)&Bs[row * BK + (((kk * 4 + kg) ^ rx) * 8)];
            }
            #pragma unroll
            for (int m = 0; m < 4; m++)
                #pragma unroll
                for (int n = 0; n < 4; n++)
                    acc[m][n] = __builtin_amdgcn_mfma_f32_16x16x32_bf16(av[m], bv[n],
                                                                        acc[m][n], 0, 0, 0);
        }
        __syncthreads();
    }
    const int r0 = brow + wr + (lane >> 4) * 4;
    const int c0 = bcol + wc + (lane & 15);
    #pragma unroll
    for (int n = 0; n < 4; n++) {
        const int col = c0 + n * 16;
        if (col < N) {
            const float bb = bias[col];
            #pragma unroll
            for (int m = 0; m < 4; m++) {
                #pragma unroll
                for (int r = 0; r < 4; r++) {
                    const int row = r0 + m * 16 + r;
                    float v = acc[m][n][r] + bb;
                    if (RELU) v = fmaxf(v, 0.f);
                    if (F32OUT) Cf[(long)row * ldc + col] = v;
                    else        Cb[(long)row * ldc + col] = f2bs(v);
                }
            }
        }
    }
}

// ---------------- BatchNorm: finalize / apply ----------------
__global__ void k_bnfin(float* __restrict__ sums, const float* __restrict__ g,
                        const float* __restrict__ be, int ncols) {
    const int c = blockIdx.x * blockDim.x + threadIdx.x;
    const float m   = sums[c] * (1.f / NB);
    const float var = sums[ncols + c] * (1.f / NB) - m * m;
    const float sc  = rsqrtf(var + EPSV) * g[c];
    sums[c] = sc;
    sums[ncols + c] = be[c] - m * sc;
}

template <int RELU>
__global__ void k_bnapply(unsigned short* __restrict__ t, const float* __restrict__ sums,
                          int ncols) {
    const long i  = ((long)blockIdx.x * blockDim.x + threadIdx.x) * 8;
    const int  c0 = (int)(i & (ncols - 1));
    uint4 v = *(uint4*)(t + i);
    unsigned int us[8] = {v.x & 0xffffu, v.x >> 16, v.y & 0xffffu, v.y >> 16,
                          v.z & 0xffffu, v.z >> 16, v.w & 0xffffu, v.w >> 16};
    unsigned int po[8];
    #pragma unroll
    for (int j = 0; j < 8; j++) {
        const int c = c0 + j;
        float val = bs2f(us[j]) * sums[c] + sums[ncols + c];
        if (RELU) val = fmaxf(val, 0.f);
        po[j] = f2bs(val);
    }
    uint4 o;
    o.x = po[0] | (po[1] << 16); o.y = po[2] | (po[3] << 16);
    o.z = po[4] | (po[5] << 16); o.w = po[6] | (po[7] << 16);
    *(uint4*)(t + i) = o;
}

// ---------------- logit losses ----------------
__global__ __launch_bounds__(256) void k_logitloss(const float* __restrict__ out,
                            const int* __restrict__ y,
                            const int* __restrict__ order, const int* __restrict__ s1,
                            const int* __restrict__ s2, const float* __restrict__ lamp,
                            float* __restrict__ acc) {
    const int lane = threadIdx.x & 63;
    const int wv   = threadIdx.x >> 6;
    const int wid  = blockIdx.x * 4 + wv;
    const int nw   = gridDim.x * 4;
    const float lam = lamp[0];
    float ce = 0.f, d1 = 0.f, d2 = 0.f;
    for (int i = wid; i < NB; i += nw) {
        const float* o  = out + (long)i * NCP;
        const float* o2 = out + (long)s1[i] * NCP;
        const float* o3 = out + (long)s2[i] * NCP;
        float v[6];
        float mx = -1e30f;
        #pragma unroll
        for (int j = 0; j < 6; j++) {
            const int c = lane + j * 64;
            if (c < NC) {
                const float a = o[c], b = o2[c], cc = o3[c];
                const float mix = lam * b + (1.f - lam) * cc;
                v[j] = a;
                d1 += (a - b) * (a - b);
                d2 += (a - mix) * (a - mix);
                mx = fmaxf(mx, a);
            } else v[j] = -1e30f;
        }
        #pragma unroll
        for (int off = 32; off; off >>= 1) mx = fmaxf(mx, __shfl_xor(mx, off));
        float se = 0.f;
        #pragma unroll
        for (int j = 0; j < 6; j++) se += expf(v[j] - mx);
        #pragma unroll
        for (int off = 32; off; off >>= 1) se += __shfl_xor(se, off);
        if (lane == 0) {
            const int yv = y[order[i]];
            ce += mx + logf(se) - o[yv];
        }
    }
    #pragma unroll
    for (int off = 32; off; off >>= 1) {
        d1 += __shfl_xor(d1, off);
        d2 += __shfl_xor(d2, off);
    }
    __shared__ float red[4][3];
    if (lane == 0) { red[wv][0] = ce; red[wv][1] = d1; red[wv][2] = d2; }
    __syncthreads();
    if (threadIdx.x == 0) {
        atomicAdd(&acc[0], red[0][0] + red[1][0] + red[2][0] + red[3][0]);
        atomicAdd(&acc[1], red[0][1] + red[1][1] + red[2][1] + red[3][1]);
        atomicAdd(&acc[2], red[0][2] + red[1][2] + red[2][2] + red[3][2]);
    }
}

// ---------------- proj feature losses (BN applied inline from stats) ----------------
__global__ __launch_bounds__(256) void k_featloss(const unsigned short* __restrict__ t3,
                           const float* __restrict__ st,
                           const int* __restrict__ s1,
                           const int* __restrict__ s2, const float* __restrict__ lamp,
                           float* __restrict__ acc) {
    const int t = threadIdx.x;   // 256, cols t*8..t*8+7
    const float lam = lamp[0];
    float sc[8], sh[8];
    #pragma unroll
    for (int j = 0; j < 8; j++) { sc[j] = st[t * 8 + j]; sh[j] = st[NF + t * 8 + j]; }
    float d1 = 0.f, d2 = 0.f;
    for (int i = blockIdx.x; i < NB; i += gridDim.x) {
        uint4 a = ((const uint4*)(t3 + (long)i * NF))[t];
        uint4 b = ((const uint4*)(t3 + (long)s1[i] * NF))[t];
        uint4 c = ((const uint4*)(t3 + (long)s2[i] * NF))[t];
        unsigned int ua[8] = {a.x & 0xffffu, a.x >> 16, a.y & 0xffffu, a.y >> 16,
                              a.z & 0xffffu, a.z >> 16, a.w & 0xffffu, a.w >> 16};
        unsigned int ub[8] = {b.x & 0xffffu, b.x >> 16, b.y & 0xffffu, b.y >> 16,
                              b.z & 0xffffu, b.z >> 16, b.w & 0xffffu, b.w >> 16};
        unsigned int uc[8] = {c.x & 0xffffu, c.x >> 16, c.y & 0xffffu, c.y >> 16,
                              c.z & 0xffffu, c.z >> 16, c.w & 0xffffu, c.w >> 16};
        #pragma unroll
        for (int j = 0; j < 8; j++) {
            float pa = sc[j] * bs2f(ua[j]) + sh[j];
            float pb = sc[j] * bs2f(ub[j]) + sh[j];
            float pc = sc[j] * bs2f(uc[j]) + sh[j];
            float mix = lam * pb + (1.f - lam) * pc;
            d1 += (pa - pb) * (pa - pb);
            d2 += (pa - mix) * (pa - mix);
        }
    }
    #pragma unroll
    for (int off = 32; off; off >>= 1) {
        d1 += __shfl_xor(d1, off);
        d2 += __shfl_xor(d2, off);
    }
    __shared__ float r1[4], r2[4];
    if ((t & 63) == 0) { r1[t >> 6] = d1; r2[t >> 6] = d2; }
    __syncthreads();
    if (t == 0) {
        atomicAdd(&acc[3], r1[0] + r1[1] + r1[2] + r1[3]);
        atomicAdd(&acc[4], r2[0] + r2[1] + r2[2] + r2[3]);
    }
}

__global__ void k_final(const float* __restrict__ acc, const float* __restrict__ lamp,
                        float* __restrict__ outp) {
    const float lam = lamp[0];
    const float cl  = acc[0] * (1.f / NB);
    const float Lil = acc[1] * (1.f / ((float)NB * NC));
    const float Lhl = acc[2] * (1.f / ((float)NB * NC));
    const float Lif = 0.3f * acc[3] * (1.f / ((float)NB * NF));
    const float Lhf = 0.3f * acc[4] * (1.f / ((float)NB * NF));
    const float Cs  = fminf(cl, 1.f);
    outp[0] = cl + Cs * (lam * (Lil + Lif) + (1.f - lam) * (Lhl + Lhf));
}

extern "C" void kernel_launch(void* const* d_in, const int* in_sizes, int n_in,
                              void* d_out, int out_size, void* d_ws, size_t ws_size,
                              hipStream_t stream) {
    const float* x   = (const float*)d_in[0];
    const float* lam = (const float*)d_in[1];
    const float* Wf  = (const float*)d_in[2];
    const float* bf_ = (const float*)d_in[3];
    const float* W1  = (const float*)d_in[4];
    const float* b1  = (const float*)d_in[5];
    const float* g1  = (const float*)d_in[6];
    const float* be1 = (const float*)d_in[7];
    const float* W2  = (const float*)d_in[8];
    const float* b2  = (const float*)d_in[9];
    const float* g2  = (const float*)d_in[10];
    const float* be2 = (const float*)d_in[11];
    const float* W3  = (const float*)d_in[12];
    const float* b3  = (const float*)d_in[13];
    const float* g3  = (const float*)d_in[14];
    const float* be3 = (const float*)d_in[15];
    const float* Wc  = (const float*)d_in[16];
    const float* bc  = (const float*)d_in[17];
    const int* y     = (const int*)d_in[18];
    const int* order = (const int*)d_in[19];
    const int* s1    = (const int*)d_in[20];
    const int* s2    = (const int*)d_in[21];
    float* outp = (float*)d_out;

    char* ws = (char*)d_ws;
    const size_t SZ_ACT = (size_t)NB * 2048 * 2;                    // 32 MiB
    unsigned short* bufA = (unsigned short*)(ws);                   // xg -> t2/h2
    unsigned short* bufB = (unsigned short*)(ws + SZ_ACT);          // feat -> t3
    unsigned short* bufC = (unsigned short*)(ws + 2 * SZ_ACT);      // t1/h1
    float* outbuf = (float*)(ws + 3 * SZ_ACT);                      // 8192 x 384 f32
    size_t off = 3 * SZ_ACT + (size_t)NB * NCP * 4;
    unsigned short* WT0 = (unsigned short*)(ws + off); off += (size_t)2048 * 2048 * 2;
    unsigned short* WT1 = (unsigned short*)(ws + off); off += (size_t)2048 * 2048 * 2;
    unsigned short* WT2 = (unsigned short*)(ws + off); off += (size_t)2048 * 2048 * 2;
    unsigned short* WT3 = (unsigned short*)(ws + off); off += (size_t)2048 * 2048 * 2;
    unsigned short* WCT = (unsigned short*)(ws + off); off += (size_t)NCP * 2048 * 2;
    float* stats = (float*)(ws + off);                               // 3 x 4096 floats
    float* accs  = stats + 3 * 4096;                                 // 5 floats used

    hipMemsetAsync(stats, 0, (3 * 4096 + 8) * sizeof(float), stream);

    dim3 tb(32, 8);
    k_transpose<<<dim3(64, 64), tb, 0, stream>>>(Wf, WT0, 2048, 2048, 2048);
    k_transpose<<<dim3(64, 64), tb, 0, stream>>>(W1, WT1, 2048, 2048, 2048);
    k_transpose<<<dim3(64, 64), tb, 0, stream>>>(W2, WT2, 2048, 2048, 2048);
    k_transpose<<<dim3(64, 64), tb, 0, stream>>>(W3, WT3, 2048, 2048, 2048);
    k_transpose<<<dim3(12, 64), tb, 0, stream>>>(Wc, WCT, 2048, NC, NCP);

    k_gather<<<NB, 256, 0, stream>>>(x, order, bufA);

    // feat = relu(xg @ Wf + bf)
    k_gemm256<1, 0><<<512, 512, 0, stream>>>(bufA, WT0, bf_, bufB, nullptr);
    // out = feat @ Wc + bc   (f32, ldc=384) — 128x128 kernel
    k_gemm<0, 1><<<dim3(64, 3), 256, 0, stream>>>(bufB, WCT, bc, nullptr, outbuf, NB, NC, 2048, NCP);
    // t1 = feat @ W1 + b1 (+ fused BN stats) ; h1 = relu(bn(t1))
    k_gemm256<0, 1><<<512, 512, 0, stream>>>(bufB, WT1, b1, bufC, stats);
    k_bnfin<<<8, 256, 0, stream>>>(stats, g1, be1, 2048);
    k_bnapply<1><<<8192, 256, 0, stream>>>(bufC, stats, 2048);
    // t2 = h1 @ W2 + b2 (+ stats) ; h2 = relu(bn(t2))
    k_gemm256<0, 1><<<512, 512, 0, stream>>>(bufC, WT2, b2, bufA, stats + 4096);
    k_bnfin<<<8, 256, 0, stream>>>(stats + 4096, g2, be2, 2048);
    k_bnapply<1><<<8192, 256, 0, stream>>>(bufA, stats + 4096, 2048);
    // t3 = h2 @ W3 + b3 (+ stats) ; proj consumed directly by featloss
    k_gemm256<0, 1><<<512, 512, 0, stream>>>(bufA, WT3, b3, bufB, stats + 8192);
    k_bnfin<<<8, 256, 0, stream>>>(stats + 8192, g3, be3, 2048);

    k_logitloss<<<256, 256, 0, stream>>>(outbuf, y, order, s1, s2, lam, accs);
    k_featloss<<<512, 256, 0, stream>>>(bufB, stats + 8192, s1, s2, lam, accs);
    k_final<<<1, 1, 0, stream>>>(accs, lam, outp);
}

// Round 7
// 444.334 us; speedup vs baseline: 1.1481x; 1.1481x over previous
//
#include <hip/hip_runtime.h>

#define NB   8192
#define NF   2048
#define NC   345
#define NCP  384
#define EPSV 1e-5f

typedef __bf16 bf16x8 __attribute__((ext_vector_type(8)));
typedef float  f32x4  __attribute__((ext_vector_type(4)));

__device__ __forceinline__ float bs2f(unsigned int u) { return __uint_as_float(u << 16); }
__device__ __forceinline__ unsigned short f2bs(float f) {
    unsigned int u = __float_as_uint(f);
    u += 0x7fffu + ((u >> 16) & 1u);   // round-to-nearest-even
    return (unsigned short)(u >> 16);
}

#define GLD16(g, l)                                                                     \
    __builtin_amdgcn_global_load_lds((const __attribute__((address_space(1))) void*)(g),\
                                     (__attribute__((address_space(3))) void*)(l),      \
                                     16, 0, 0)

// ---------------- gather + cast x rows: xg[i] = bf16(x[order[i]]) ----------------
__global__ void k_gather(const float* __restrict__ x, const int* __restrict__ order,
                         unsigned short* __restrict__ xg) {
    const int row = blockIdx.x;
    const long src = order[row];
    const float4* xr = (const float4*)(x + src * 2048);
    float4 a = xr[threadIdx.x * 2 + 0];
    float4 b = xr[threadIdx.x * 2 + 1];
    uint4 o;
    o.x = (unsigned)f2bs(a.x) | ((unsigned)f2bs(a.y) << 16);
    o.y = (unsigned)f2bs(a.z) | ((unsigned)f2bs(a.w) << 16);
    o.z = (unsigned)f2bs(b.x) | ((unsigned)f2bs(b.y) << 16);
    o.w = (unsigned)f2bs(b.z) | ((unsigned)f2bs(b.w) << 16);
    ((uint4*)(xg + (long)row * 2048))[threadIdx.x] = o;
}

// ---------------- transpose+cast weights: Wt[n][k] = bf16(W[k][n]) ----------------
__global__ void k_transpose(const float* __restrict__ W, unsigned short* __restrict__ Wt,
                            int K, int N, int Npad) {
    __shared__ float tile[32][33];
    const int n0 = blockIdx.x * 32, k0 = blockIdx.y * 32;
    const int tx = threadIdx.x, ty = threadIdx.y;   // 32 x 8
    #pragma unroll
    for (int i = 0; i < 32; i += 8) {
        int n = n0 + tx, k = k0 + ty + i;
        tile[ty + i][tx] = (n < N) ? W[(long)k * N + n] : 0.f;
    }
    __syncthreads();
    #pragma unroll
    for (int i = 0; i < 32; i += 8) {
        int n = n0 + ty + i, k = k0 + tx;
        if (n < Npad) Wt[(long)n * K + k] = f2bs(tile[tx][ty + i]);
    }
}

// ========== 256x256 bf16 GEMM with register-double-buffered fragments =========
// BK=32 subtiles, 4 LDS subtile buffers (128 KiB), prefetch distance 2.
// Per step t: issue ds_reads for subtile t+1 (opposite reg bank) + stage(t+3),
// THEN 32 MFMA on subtile t from the already-loaded bank -> LDS port and VMEM
// work DURING the MFMA burst. VMW4 sits before each barrier so the barrier
// certifies the stage needed by the NEXT step's reads (safe cross-wave
// visibility: per-wave vmcnt -> barrier -> read). stage(t+3) overwrites buf
// (t-1)&3 whose reads drained >=1 barrier earlier. Compiler inserts the fine
// lgkmcnt before each MFMA bank use.
#define BARX  do { asm volatile("" ::: "memory"); __builtin_amdgcn_s_barrier(); \
                   asm volatile("" ::: "memory"); } while (0)
#define VMW4  asm volatile("s_waitcnt vmcnt(4)" ::: "memory")
#define VMW0  asm volatile("s_waitcnt vmcnt(0)" ::: "memory")

#define RDX(u, AV, BV) do {                                                            \
    const unsigned short* A_ = &L[((u) & 3) * 16384];                                  \
    const unsigned short* B_ = A_ + 8192;                                              \
    _Pragma("unroll") for (int m_ = 0; m_ < 8; m_++)                                   \
        AV[m_] = *(const bf16x8*)&A_[(m_ * 16 + frow) * 64 + sA * 8];                  \
    _Pragma("unroll") for (int n_ = 0; n_ < 4; n_++)                                   \
        BV[n_] = *(const bf16x8*)&B_[((wn & 1) * 64 + n_ * 16 + frow) * 64 + sB * 8];  \
} while (0)

#define MMX(AV, BV) do {                                                               \
    __builtin_amdgcn_s_setprio(1);                                                     \
    _Pragma("unroll") for (int n_ = 0; n_ < 4; n_++)                                   \
    _Pragma("unroll") for (int m_ = 0; m_ < 8; m_++)                                   \
        acc[m_][n_] = __builtin_amdgcn_mfma_f32_16x16x32_bf16(BV[n_], AV[m_],          \
                                                              acc[m_][n_], 0, 0, 0);  \
    __builtin_amdgcn_s_setprio(0);                                                     \
} while (0)

template <int RELU, int STATS>
__global__ __launch_bounds__(512, 2) void k_gemm256(
    const unsigned short* __restrict__ A,
    const unsigned short* __restrict__ Bt,
    const float* __restrict__ bias,
    unsigned short* __restrict__ C,
    float* __restrict__ stats,
    int N, int K) {
    __shared__ unsigned short L[4 * 16384];   // 128 KiB
    const int tid  = threadIdx.x;
    const int lane = tid & 63;
    const int wv   = tid >> 6;       // 8 waves: 2M x 4N
    const int frow = lane & 15;
    const int kg   = lane >> 4;
    const int wm   = wv >> 2;
    const int wn   = wv & 3;
    const int sA = (kg + 4 * wm) ^ (frow & 7);
    const int sB = (kg + 4 * (wn >> 1)) ^ (frow & 7);

    // XCD-aware block swizzle: XCD x owns M-blocks 4x..4x+3, sweeps N-blocks.
    const int id  = blockIdx.x;
    const int xcd = id & 7, kid = id >> 3;
    const int brow = (xcd * 4 + (kid & 3)) * 256;
    const int bcol = (kid >> 2) * 256;

    // per-thread staging sources (pre-swizzled so linear LDS dest matches reads)
    const unsigned short* pA[2];
    const unsigned short* pB[2];
    #pragma unroll
    for (int i = 0; i < 2; i++) {
        const int q = tid + i * 512;
        const int j = q >> 3;
        const int u = (q & 7) ^ (j & 7);
        const int r = j + 128 * (u >> 2);
        const int c = u & 3;
        pA[i] = A  + (long)(brow + r) * K + c * 8;
        pB[i] = Bt + (long)(bcol + r) * K + c * 8;
    }

    f32x4 acc[8][4];
    #pragma unroll
    for (int m = 0; m < 8; m++)
        #pragma unroll
        for (int n = 0; n < 4; n++)
            #pragma unroll
            for (int r = 0; r < 4; r++) acc[m][n][r] = 0.f;

    auto stage = [&](int s) {
        unsigned short* Lb = &L[(s & 3) * 16384];
        const int ko = s * 32;
        GLD16(pA[0] + ko, Lb + wv * 512);
        GLD16(pA[1] + ko, Lb + 4096 + wv * 512);
        GLD16(pB[0] + ko, Lb + 8192 + wv * 512);
        GLD16(pB[1] + ko, Lb + 12288 + wv * 512);
    };

    bf16x8 avA[8], bvA[4], avB[8], bvB[4];

    // prologue: stage 0,1,2 (12 loads); confirm 0 AND 1 (vmcnt<=4) pre-barrier
    stage(0); stage(1); stage(2);
    VMW4; BARX;
    RDX(0, avA, bvA);

    // main: 30 double-steps (subtiles 0..59); stage(t+3) each step
    for (int i = 0; i < 30; i++) {
        const int t = i * 2;
        RDX(t + 1, avB, bvB); stage(t + 3); MMX(avA, bvA); VMW4; BARX;
        RDX(t + 2, avA, bvA); stage(t + 4); MMX(avB, bvB); VMW4; BARX;
    }
    // t=60: last stage (63); VMW4 confirms 62 for next step's read
    RDX(61, avB, bvB); stage(63); MMX(avA, bvA); VMW4; BARX;
    // t=61: VMW0 confirms 63
    RDX(62, avA, bvA); MMX(avB, bvB); VMW0; BARX;
    // t=62, t=63
    RDX(63, avB, bvB); MMX(avA, bvA);
    MMX(avB, bvB);

    // epilogue: lane holds rows m*16+frow, cols wn*64+n*16+kg*4+{0..3} (ushort4)
    const int rbase = brow + wm * 128 + frow;
    const int cbase = bcol + wn * 64 + kg * 4;
    #pragma unroll
    for (int n = 0; n < 4; n++) {
        const int col = cbase + n * 16;
        const float4 bb = *(const float4*)&bias[col];
        float s0 = 0.f, s1 = 0.f, s2 = 0.f, s3 = 0.f;
        float q0 = 0.f, q1 = 0.f, q2 = 0.f, q3 = 0.f;
        #pragma unroll
        for (int m = 0; m < 8; m++) {
            const long row = rbase + m * 16;
            float v0 = acc[m][n][0] + bb.x;
            float v1 = acc[m][n][1] + bb.y;
            float v2 = acc[m][n][2] + bb.z;
            float v3 = acc[m][n][3] + bb.w;
            if (STATS) { s0 += v0; q0 += v0 * v0; s1 += v1; q1 += v1 * v1;
                         s2 += v2; q2 += v2 * v2; s3 += v3; q3 += v3 * v3; }
            if (RELU) { v0 = fmaxf(v0, 0.f); v1 = fmaxf(v1, 0.f);
                        v2 = fmaxf(v2, 0.f); v3 = fmaxf(v3, 0.f); }
            ushort4 st; st.x = f2bs(v0); st.y = f2bs(v1); st.z = f2bs(v2); st.w = f2bs(v3);
            *(ushort4*)&C[row * N + col] = st;
        }
        if (STATS) {
            #pragma unroll
            for (int off = 1; off <= 8; off <<= 1) {
                s0 += __shfl_xor(s0, off); s1 += __shfl_xor(s1, off);
                s2 += __shfl_xor(s2, off); s3 += __shfl_xor(s3, off);
                q0 += __shfl_xor(q0, off); q1 += __shfl_xor(q1, off);
                q2 += __shfl_xor(q2, off); q3 += __shfl_xor(q3, off);
            }
            if (frow == 0) {   // lanes 0,16,32,48: kg 0..3, disjoint col sets
                atomicAdd(&stats[col + 0], s0); atomicAdd(&stats[col + 1], s1);
                atomicAdd(&stats[col + 2], s2); atomicAdd(&stats[col + 3], s3);
                atomicAdd(&stats[N + col + 0], q0); atomicAdd(&stats[N + col + 1], q1);
                atomicAdd(&stats[N + col + 2], q2); atomicAdd(&stats[N + col + 3], q3);
            }
        }
    }
}

// ---------------- 128x128 GEMM (classifier, f32 out) ----------------
template <int RELU, int F32OUT>
__global__ __launch_bounds__(256) void k_gemm(const unsigned short* __restrict__ A,
                                              const unsigned short* __restrict__ Bt,
                                              const float* __restrict__ bias,
                                              unsigned short* __restrict__ Cb,
                                              float* __restrict__ Cf,
                                              int M, int N, int K, int ldc) {
    constexpr int BK = 64;
    __shared__ unsigned short As[128 * BK];
    __shared__ unsigned short Bs[128 * BK];
    const int tid  = threadIdx.x;
    const int lane = tid & 63;
    const int wv   = tid >> 6;
    const int brow = blockIdx.x * 128;
    const int bcol = blockIdx.y * 128;
    const int wr   = (wv >> 1) * 64;
    const int wc   = (wv & 1) * 64;
    const int frow = lane & 15;
    const int kg   = lane >> 4;
    const int rx   = frow & 7;
    const int srow  = lane >> 3;
    const int sslot = (lane & 7) ^ srow;

    f32x4 acc[4][4];
    #pragma unroll
    for (int m = 0; m < 4; m++)
        #pragma unroll
        for (int n = 0; n < 4; n++)
            #pragma unroll
            for (int r = 0; r < 4; r++) acc[m][n][r] = 0.f;

    for (int kt = 0; kt < K; kt += BK) {
        #pragma unroll
        for (int i = 0; i < 4; i++) {
            const int c = wv * 4 + i;
            const int r = c * 8 + srow;
            GLD16(A + (long)(brow + r) * K + kt + sslot * 8, &As[c * 512]);
        }
        #pragma unroll
        for (int i = 0; i < 4; i++) {
            const int c = wv * 4 + i;
            const int r = c * 8 + srow;
            GLD16(Bt + (long)(bcol + r) * K + kt + sslot * 8, &Bs[c * 512]);
        }
        __syncthreads();
        #pragma unroll
        for (int kk = 0; kk < 2; kk++) {
            bf16x8 av[4], bv[4];
            #pragma unroll
            for (int m = 0; m < 4; m++) {
                const int row = wr + m * 16 + frow;
                av[m] = *(const bf16x8*)&As[row * BK + (((kk * 4 + kg) ^ rx) * 8)];
            }
            #pragma unroll
            for (int n = 0; n < 4; n++) {
                const int row = wc + n * 16 + frow;
                bv[n] = *(const bf16x8*)&Bs[row * BK + (((kk * 4 + kg) ^ rx) * 8)];
            }
            #pragma unroll
            for (int m = 0; m < 4; m++)
                #pragma unroll
                for (int n = 0; n < 4; n++)
                    acc[m][n] = __builtin_amdgcn_mfma_f32_16x16x32_bf16(av[m], bv[n],
                                                                        acc[m][n], 0, 0, 0);
        }
        __syncthreads();
    }
    const int r0 = brow + wr + (lane >> 4) * 4;
    const int c0 = bcol + wc + (lane & 15);
    #pragma unroll
    for (int n = 0; n < 4; n++) {
        const int col = c0 + n * 16;
        if (col < N) {
            const float bb = bias[col];
            #pragma unroll
            for (int m = 0; m < 4; m++) {
                #pragma unroll
                for (int r = 0; r < 4; r++) {
                    const int row = r0 + m * 16 + r;
                    float v = acc[m][n][r] + bb;
                    if (RELU) v = fmaxf(v, 0.f);
                    if (F32OUT) Cf[(long)row * ldc + col] = v;
                    else        Cb[(long)row * ldc + col] = f2bs(v);
                }
            }
        }
    }
}

// ---------------- BatchNorm: finalize / apply ----------------
__global__ void k_bnfin(float* __restrict__ sums, const float* __restrict__ g,
                        const float* __restrict__ be, int ncols) {
    const int c = blockIdx.x * blockDim.x + threadIdx.x;
    const float m   = sums[c] * (1.f / NB);
    const float var = sums[ncols + c] * (1.f / NB) - m * m;
    const float sc  = rsqrtf(var + EPSV) * g[c];
    sums[c] = sc;
    sums[ncols + c] = be[c] - m * sc;
}

template <int RELU>
__global__ void k_bnapply(unsigned short* __restrict__ t, const float* __restrict__ sums,
                          int ncols) {
    const long i  = ((long)blockIdx.x * blockDim.x + threadIdx.x) * 8;
    const int  c0 = (int)(i & (ncols - 1));
    uint4 v = *(uint4*)(t + i);
    unsigned int us[8] = {v.x & 0xffffu, v.x >> 16, v.y & 0xffffu, v.y >> 16,
                          v.z & 0xffffu, v.z >> 16, v.w & 0xffffu, v.w >> 16};
    unsigned int po[8];
    #pragma unroll
    for (int j = 0; j < 8; j++) {
        const int c = c0 + j;
        float val = bs2f(us[j]) * sums[c] + sums[ncols + c];
        if (RELU) val = fmaxf(val, 0.f);
        po[j] = f2bs(val);
    }
    uint4 o;
    o.x = po[0] | (po[1] << 16); o.y = po[2] | (po[3] << 16);
    o.z = po[4] | (po[5] << 16); o.w = po[6] | (po[7] << 16);
    *(uint4*)(t + i) = o;
}

// ---------------- logit losses ----------------
__global__ __launch_bounds__(256) void k_logitloss(const float* __restrict__ out,
                            const int* __restrict__ y,
                            const int* __restrict__ order, const int* __restrict__ s1,
                            const int* __restrict__ s2, const float* __restrict__ lamp,
                            float* __restrict__ acc) {
    const int lane = threadIdx.x & 63;
    const int wv   = threadIdx.x >> 6;
    const int wid  = blockIdx.x * 4 + wv;
    const int nw   = gridDim.x * 4;
    const float lam = lamp[0];
    float ce = 0.f, d1 = 0.f, d2 = 0.f;
    for (int i = wid; i < NB; i += nw) {
        const float* o  = out + (long)i * NCP;
        const float* o2 = out + (long)s1[i] * NCP;
        const float* o3 = out + (long)s2[i] * NCP;
        float v[6];
        float mx = -1e30f;
        #pragma unroll
        for (int j = 0; j < 6; j++) {
            const int c = lane + j * 64;
            if (c < NC) {
                const float a = o[c], b = o2[c], cc = o3[c];
                const float mix = lam * b + (1.f - lam) * cc;
                v[j] = a;
                d1 += (a - b) * (a - b);
                d2 += (a - mix) * (a - mix);
                mx = fmaxf(mx, a);
            } else v[j] = -1e30f;
        }
        #pragma unroll
        for (int off = 32; off; off >>= 1) mx = fmaxf(mx, __shfl_xor(mx, off));
        float se = 0.f;
        #pragma unroll
        for (int j = 0; j < 6; j++) se += expf(v[j] - mx);
        #pragma unroll
        for (int off = 32; off; off >>= 1) se += __shfl_xor(se, off);
        if (lane == 0) {
            const int yv = y[order[i]];
            ce += mx + logf(se) - o[yv];
        }
    }
    #pragma unroll
    for (int off = 32; off; off >>= 1) {
        d1 += __shfl_xor(d1, off);
        d2 += __shfl_xor(d2, off);
    }
    __shared__ float red[4][3];
    if (lane == 0) { red[wv][0] = ce; red[wv][1] = d1; red[wv][2] = d2; }
    __syncthreads();
    if (threadIdx.x == 0) {
        atomicAdd(&acc[0], red[0][0] + red[1][0] + red[2][0] + red[3][0]);
        atomicAdd(&acc[1], red[0][1] + red[1][1] + red[2][1] + red[3][1]);
        atomicAdd(&acc[2], red[0][2] + red[1][2] + red[2][2] + red[3][2]);
    }
}

// ---------------- proj feature losses (BN applied inline from stats) ----------------
__global__ __launch_bounds__(256) void k_featloss(const unsigned short* __restrict__ t3,
                           const float* __restrict__ st,
                           const int* __restrict__ s1,
                           const int* __restrict__ s2, const float* __restrict__ lamp,
                           float* __restrict__ acc) {
    const int t = threadIdx.x;   // 256, cols t*8..t*8+7
    const float lam = lamp[0];
    float sc[8], sh[8];
    #pragma unroll
    for (int j = 0; j < 8; j++) { sc[j] = st[t * 8 + j]; sh[j] = st[NF + t * 8 + j]; }
    float d1 = 0.f, d2 = 0.f;
    for (int i = blockIdx.x; i < NB; i += gridDim.x) {
        uint4 a = ((const uint4*)(t3 + (long)i * NF))[t];
        uint4 b = ((const uint4*)(t3 + (long)s1[i] * NF))[t];
        uint4 c = ((const uint4*)(t3 + (long)s2[i] * NF))[t];
        unsigned int ua[8] = {a.x & 0xffffu, a.x >> 16, a.y & 0xffffu, a.y >> 16,
                              a.z & 0xffffu, a.z >> 16, a.w & 0xffffu, a.w >> 16};
        unsigned int ub[8] = {b.x & 0xffffu, b.x >> 16, b.y & 0xffffu, b.y >> 16,
                              b.z & 0xffffu, b.z >> 16, b.w & 0xffffu, b.w >> 16};
        unsigned int uc[8] = {c.x & 0xffffu, c.x >> 16, c.y & 0xffffu, c.y >> 16,
                              c.z & 0xffffu, c.z >> 16, c.w & 0xffffu, c.w >> 16};
        #pragma unroll
        for (int j = 0; j < 8; j++) {
            float pa = sc[j] * bs2f(ua[j]) + sh[j];
            float pb = sc[j] * bs2f(ub[j]) + sh[j];
            float pc = sc[j] * bs2f(uc[j]) + sh[j];
            float mix = lam * pb + (1.f - lam) * pc;
            d1 += (pa - pb) * (pa - pb);
            d2 += (pa - mix) * (pa - mix);
        }
    }
    #pragma unroll
    for (int off = 32; off; off >>= 1) {
        d1 += __shfl_xor(d1, off);
        d2 += __shfl_xor(d2, off);
    }
    __shared__ float r1[4], r2[4];
    if ((t & 63) == 0) { r1[t >> 6] = d1; r2[t >> 6] = d2; }
    __syncthreads();
    if (t == 0) {
        atomicAdd(&acc[3], r1[0] + r1[1] + r1[2] + r1[3]);
        atomicAdd(&acc[4], r2[0] + r2[1] + r2[2] + r2[3]);
    }
}

__global__ void k_final(const float* __restrict__ acc, const float* __restrict__ lamp,
                        float* __restrict__ outp) {
    const float lam = lamp[0];
    const float cl  = acc[0] * (1.f / NB);
    const float Lil = acc[1] * (1.f / ((float)NB * NC));
    const float Lhl = acc[2] * (1.f / ((float)NB * NC));
    const float Lif = 0.3f * acc[3] * (1.f / ((float)NB * NF));
    const float Lhf = 0.3f * acc[4] * (1.f / ((float)NB * NF));
    const float Cs  = fminf(cl, 1.f);
    outp[0] = cl + Cs * (lam * (Lil + Lif) + (1.f - lam) * (Lhl + Lhf));
}

extern "C" void kernel_launch(void* const* d_in, const int* in_sizes, int n_in,
                              void* d_out, int out_size, void* d_ws, size_t ws_size,
                              hipStream_t stream) {
    const float* x   = (const float*)d_in[0];
    const float* lam = (const float*)d_in[1];
    const float* Wf  = (const float*)d_in[2];
    const float* bf_ = (const float*)d_in[3];
    const float* W1  = (const float*)d_in[4];
    const float* b1  = (const float*)d_in[5];
    const float* g1  = (const float*)d_in[6];
    const float* be1 = (const float*)d_in[7];
    const float* W2  = (const float*)d_in[8];
    const float* b2  = (const float*)d_in[9];
    const float* g2  = (const float*)d_in[10];
    const float* be2 = (const float*)d_in[11];
    const float* W3  = (const float*)d_in[12];
    const float* b3  = (const float*)d_in[13];
    const float* g3  = (const float*)d_in[14];
    const float* be3 = (const float*)d_in[15];
    const float* Wc  = (const float*)d_in[16];
    const float* bc  = (const float*)d_in[17];
    const int* y     = (const int*)d_in[18];
    const int* order = (const int*)d_in[19];
    const int* s1    = (const int*)d_in[20];
    const int* s2    = (const int*)d_in[21];
    float* outp = (float*)d_out;

    char* ws = (char*)d_ws;
    const size_t SZ_ACT = (size_t)NB * 2048 * 2;                    // 32 MiB
    unsigned short* bufA = (unsigned short*)(ws);                   // xg -> t2/h2
    unsigned short* bufB = (unsigned short*)(ws + SZ_ACT);          // feat -> t3
    unsigned short* bufC = (unsigned short*)(ws + 2 * SZ_ACT);      // t1/h1
    float* outbuf = (float*)(ws + 3 * SZ_ACT);                      // 8192 x 384 f32
    size_t off = 3 * SZ_ACT + (size_t)NB * NCP * 4;
    unsigned short* WT0 = (unsigned short*)(ws + off); off += (size_t)2048 * 2048 * 2;
    unsigned short* WT1 = (unsigned short*)(ws + off); off += (size_t)2048 * 2048 * 2;
    unsigned short* WT2 = (unsigned short*)(ws + off); off += (size_t)2048 * 2048 * 2;
    unsigned short* WT3 = (unsigned short*)(ws + off); off += (size_t)2048 * 2048 * 2;
    unsigned short* WCT = (unsigned short*)(ws + off); off += (size_t)NCP * 2048 * 2;
    float* stats = (float*)(ws + off);                               // 3 x 4096 floats
    float* accs  = stats + 3 * 4096;                                 // 5 floats used

    hipMemsetAsync(stats, 0, (3 * 4096 + 8) * sizeof(float), stream);

    dim3 tb(32, 8);
    k_transpose<<<dim3(64, 64), tb, 0, stream>>>(Wf, WT0, 2048, 2048, 2048);
    k_transpose<<<dim3(64, 64), tb, 0, stream>>>(W1, WT1, 2048, 2048, 2048);
    k_transpose<<<dim3(64, 64), tb, 0, stream>>>(W2, WT2, 2048, 2048, 2048);
    k_transpose<<<dim3(64, 64), tb, 0, stream>>>(W3, WT3, 2048, 2048, 2048);
    k_transpose<<<dim3(12, 64), tb, 0, stream>>>(Wc, WCT, 2048, NC, NCP);

    k_gather<<<NB, 256, 0, stream>>>(x, order, bufA);

    // feat = relu(xg @ Wf + bf)
    k_gemm256<1, 0><<<256, 512, 0, stream>>>(bufA, WT0, bf_, bufB, nullptr, 2048, 2048);
    // out = feat @ Wc + bc   (f32, ldc=384) — 128x128 kernel
    k_gemm<0, 1><<<dim3(64, 3), 256, 0, stream>>>(bufB, WCT, bc, nullptr, outbuf, NB, NC, 2048, NCP);
    // t1 = feat @ W1 + b1 (+ fused BN stats) ; h1 = relu(bn(t1))
    k_gemm256<0, 1><<<256, 512, 0, stream>>>(bufB, WT1, b1, bufC, stats, 2048, 2048);
    k_bnfin<<<8, 256, 0, stream>>>(stats, g1, be1, 2048);
    k_bnapply<1><<<8192, 256, 0, stream>>>(bufC, stats, 2048);
    // t2 = h1 @ W2 + b2 (+ stats) ; h2 = relu(bn(t2))
    k_gemm256<0, 1><<<256, 512, 0, stream>>>(bufC, WT2, b2, bufA, stats + 4096, 2048, 2048);
    k_bnfin<<<8, 256, 0, stream>>>(stats + 4096, g2, be2, 2048);
    k_bnapply<1><<<8192, 256, 0, stream>>>(bufA, stats + 4096, 2048);
    // t3 = h2 @ W3 + b3 (+ stats) ; proj consumed directly by featloss
    k_gemm256<0, 1><<<256, 512, 0, stream>>>(bufA, WT3, b3, bufB, stats + 8192, 2048, 2048);
    k_bnfin<<<8, 256, 0, stream>>>(stats + 8192, g3, be3, 2048);

    k_logitloss<<<256, 256, 0, stream>>>(outbuf, y, order, s1, s2, lam, accs);
    k_featloss<<<512, 256, 0, stream>>>(bufB, stats + 8192, s1, s2, lam, accs);
    k_final<<<1, 1, 0, stream>>>(accs, lam, outp);
}